// Round 7
// baseline (1963.905 us; speedup 1.0000x reference)
//
#include <hip/hip_runtime.h>

#define N_NODES 50000
#define HIDDEN  256
#define ANNOT   32
#define NTYPES  4
#define EPT     75000
#define CAPA    32   // total in-degree cap; Poisson(6) -> P(>32) ~ 1e-16

typedef __attribute__((ext_vector_type(4))) float    f32x4;
typedef __attribute__((ext_vector_type(8))) _Float16 f16x8;
typedef __attribute__((ext_vector_type(4))) _Float16 f16x4;
typedef _Float16 half_t;

#define MFMA16(a,b,c) __builtin_amdgcn_mfma_f32_16x16x32_f16((a),(b),(c),0,0,0)

__device__ __forceinline__ void gload16(const void* g, void* l) {
    __builtin_amdgcn_global_load_lds((const __attribute__((address_space(1))) void*)g,
                                     (__attribute__((address_space(3))) void*)l, 16, 0, 0);
}

// ---------------- flat fp32 -> fp16 convert ----------------
__global__ void k_cvt(const float* __restrict__ in, half_t* __restrict__ out, int n) {
    int i = blockIdx.x * blockDim.x + threadIdx.x;
    if (i < n) out[i] = (half_t)in[i];
}

// GRU weights -> [layer][yb2][chunk16][kc4][gcol384][e8]
// K axis: chunks 0-7 = h-part (Whh), 8-15 = inc-part (Wih); gcol = gate*128 + cl
__global__ void k_cvt_wg(const float* __restrict__ Wih, const float* __restrict__ Whh,
                         half_t* __restrict__ out) {
    int i = blockIdx.x * blockDim.x + threadIdx.x;
    if (i >= 786432) return;
    const int e = i & 7; int idx = i >> 3;
    const int gcol = idx % 384; idx /= 384;
    const int kc = idx & 3; idx >>= 2;
    const int chunk = idx & 15; idx >>= 4;
    const int yb = idx & 1;
    const int layer = idx >> 1;
    const int gate = gcol >> 7, cl = gcol & 127;
    const int k = chunk * 32 + kc * 8 + e;
    const int colf = gate * 256 + yb * 128 + cl;
    float v = (k < 256) ? Whh[((size_t)layer * 768 + colf) * 256 + k]
                        : Wih[((size_t)layer * 768 + colf) * 256 + (k - 256)];
    out[i] = (half_t)v;
}

// message weights -> [layer][yb4][chunk8][kc4][col256][e8]; Y col = yb*256+col (yb==type)
__global__ void k_cvt_wy(const float* __restrict__ Wmsg, half_t* __restrict__ out) {
    int i = blockIdx.x * blockDim.x + threadIdx.x;
    if (i >= 524288) return;
    const int e = i & 7; int idx = i >> 3;
    const int col = idx & 255; idx >>= 8;
    const int kc = idx & 3; idx >>= 2;
    const int chunk = idx & 7; idx >>= 3;
    const int yb = idx & 3;
    const int layer = idx >> 2;
    const int k = chunk * 32 + kc * 8 + e;
    out[i] = (half_t)Wmsg[(((size_t)layer * 4 + yb) * 256 + col) * 256 + k];
}

// ---------------- merged CSR: per-target packed (src*4 + type) list ----------------
__global__ void k_csr2(const int* __restrict__ edges, int* __restrict__ cnt_all,
                       int* __restrict__ cnt4, int* __restrict__ elist) {
    int i = blockIdx.x * blockDim.x + threadIdx.x;
    if (i >= NTYPES * EPT) return;
    int2 st = *reinterpret_cast<const int2*>(&edges[(size_t)i * 2]);
    const int tt = i / EPT;
    atomicAdd(&cnt4[tt * N_NODES + st.y], 1);
    int pos = atomicAdd(&cnt_all[st.y], 1);
    if (pos < CAPA) elist[(size_t)st.y * CAPA + pos] = st.x * 4 + tt;
}

// ---------------- h0 = [x | annot] @ W_hid^T + b_hid  (runs once) ----------------
__global__ __launch_bounds__(256) void k_init(
    const float* __restrict__ x, const float* __restrict__ annot,
    const half_t* __restrict__ Whid16, const float* __restrict__ b_hid,
    half_t* __restrict__ h16out)
{
    __shared__ __align__(16) half_t Atile[4 * 64 * 8];
    const int tid  = threadIdx.x;
    const int lane = tid & 63;
    const int wave = tid >> 6;
    const int n0   = blockIdx.x * 64;

    f32x4 acc[4][4] = {};

    for (int ks = 0; ks < 9; ++ks) {
        const int k0 = ks * 32;
        {
            const int c = tid >> 6, r = tid & 63;
            const int node = n0 + r;
            f16x8 hv = {};
            if (node < N_NODES) {
                const int kk = k0 + c * 8;
                const float* s = (kk < HIDDEN) ? (x + (size_t)node * HIDDEN + kk)
                                               : (annot + (size_t)node * ANNOT + (kk - HIDDEN));
                const float4* s4 = reinterpret_cast<const float4*>(s);
                float4 a0 = s4[0], a1 = s4[1];
                hv[0]=(half_t)a0.x; hv[1]=(half_t)a0.y; hv[2]=(half_t)a0.z; hv[3]=(half_t)a0.w;
                hv[4]=(half_t)a1.x; hv[5]=(half_t)a1.y; hv[6]=(half_t)a1.z; hv[7]=(half_t)a1.w;
            }
            *reinterpret_cast<f16x8*>(&Atile[(c * 64 + r) * 8]) = hv;
        }
        __syncthreads();
        const int kc = lane >> 4, rl = lane & 15;
        f16x8 af[4];
        #pragma unroll
        for (int rt = 0; rt < 4; ++rt)
            af[rt] = *reinterpret_cast<const f16x8*>(&Atile[(kc * 64 + rt * 16 + rl) * 8]);
        #pragma unroll
        for (int nt = 0; nt < 4; ++nt) {
            const int col = wave * 64 + nt * 16 + rl;
            f16x8 bf = *reinterpret_cast<const f16x8*>(&Whid16[col * 288 + k0 + kc * 8]);
            #pragma unroll
            for (int rt = 0; rt < 4; ++rt)
                acc[rt][nt] = MFMA16(af[rt], bf, acc[rt][nt]);
        }
        __syncthreads();
    }

    const int rl = lane & 15, rg = lane >> 4;
    #pragma unroll
    for (int rt = 0; rt < 4; ++rt)
        #pragma unroll
        for (int i = 0; i < 4; ++i) {
            const int row = n0 + rt * 16 + rg * 4 + i;
            if (row >= N_NODES) continue;
            #pragma unroll
            for (int nt = 0; nt < 4; ++nt) {
                const int col = wave * 64 + nt * 16 + rl;
                h16out[(size_t)row * 256 + col] = (half_t)(acc[rt][nt][i] + b_hid[col]);
            }
        }
}

// ---------------- k_y5: Y[:, yb*256..] = h16 @ W^T; A in regs, B-only LDS dbuf ----------------
// grid (782, 4), 512 thr / 8 waves (rh2 x wc4); BM=64, wave 32 rows x 64 cols; K=256, BK=32
#define Y5_STAGE(cc, DST) do {                                                         \
    const half_t* sn_ = pBy + (size_t)(cc) * 8192;                                     \
    gload16(sn_ + t * 8,        (DST) + t * 8);                                        \
    gload16(sn_ + 4096 + t * 8, (DST) + 4096 + t * 8);                                 \
} while (0)

#define Y5_LOADA(AF, cc) do {                                                          \
    _Pragma("unroll") for (int rt = 0; rt < 2; ++rt)                                   \
        (AF)[rt] = *reinterpret_cast<const f16x8*>(apY[rt] + (cc) * 32);               \
} while (0)

#define Y5_COMP(AF, BUF) do {                                                          \
    const half_t* Bq_ = (BUF) + (size_t)(kc * 256 + wc * 64 + rl) * 8;                 \
    _Pragma("unroll") for (int nt = 0; nt < 4; ++nt) {                                 \
        f16x8 bf_ = *reinterpret_cast<const f16x8*>(Bq_ + nt * 128);                   \
        _Pragma("unroll") for (int rt = 0; rt < 2; ++rt)                               \
            acc[rt][nt] = MFMA16((AF)[rt], bf_, acc[rt][nt]);                          \
    }                                                                                  \
} while (0)

__global__ __launch_bounds__(512, 8) void k_y5(
    const half_t* __restrict__ h16in, const half_t* __restrict__ Wy,
    half_t* __restrict__ Y, int layer)
{
    __shared__ __align__(16) half_t lds[16896];   // bufs 2x8192; reused as OutT [64][264]
    const int t = threadIdx.x, lane = t & 63;
    const int rh = (t >> 6) >> 2, wc = (t >> 6) & 3;
    const int n0 = blockIdx.x * 64, yb = blockIdx.y;
    const int kc = lane >> 4, rl = lane & 15;

    const half_t* apY[2];
    #pragma unroll
    for (int rt = 0; rt < 2; ++rt) {
        int node = n0 + rh * 32 + rt * 16 + rl;
        if (node > N_NODES - 1) node = N_NODES - 1;
        apY[rt] = h16in + (size_t)node * 256 + kc * 8;
    }
    const half_t* pBy = Wy + (size_t)(layer * 4 + yb) * 65536;
    half_t* buf0 = lds; half_t* buf1 = lds + 8192;

    f32x4 acc[2][4] = {};
    f16x8 afA[2], afB[2];

    Y5_STAGE(0, buf0);
    Y5_LOADA(afA, 0);
    __syncthreads();

    #pragma unroll 1
    for (int p = 0; p < 4; ++p) {
        Y5_STAGE(2 * p + 1, buf1);
        Y5_LOADA(afB, 2 * p + 1);
        Y5_COMP(afA, buf0);
        __syncthreads();
        if (p < 3) {
            Y5_STAGE(2 * p + 2, buf0);
            Y5_LOADA(afA, 2 * p + 2);
        }
        Y5_COMP(afB, buf1);
        __syncthreads();
    }

    // epilogue: transpose [64][264] in lds, coalesced f16x8 stores
    const int rg = kc;
    #pragma unroll
    for (int rt = 0; rt < 2; ++rt)
        #pragma unroll
        for (int i = 0; i < 4; ++i) {
            const int row = rh * 32 + rt * 16 + rg * 4 + i;
            #pragma unroll
            for (int nt = 0; nt < 4; ++nt)
                lds[row * 264 + wc * 64 + nt * 16 + rl] = (half_t)acc[rt][nt][i];
        }
    __syncthreads();
    #pragma unroll
    for (int p = 0; p < 4; ++p) {
        const int g = p * 512 + t, row = g >> 5, q = g & 31;
        if (n0 + row < N_NODES)
            *reinterpret_cast<f16x8*>(&Y[(size_t)(n0 + row) * 1024 + yb * 256 + q * 8]) =
                *reinterpret_cast<const f16x8*>(&lds[row * 264 + q * 8]);
    }
}

// ---------------- k_gather2: inc[v] = sum_e Y[packed_e] + sum_t cnt_t * b_t ----------------
__global__ __launch_bounds__(256) void k_gather2(
    const half_t* __restrict__ Y, const int* __restrict__ cnt_all,
    const int* __restrict__ cnt4, const int* __restrict__ elist,
    const float* __restrict__ b_msg, half_t* __restrict__ inc16, int layer)
{
    const int wave = threadIdx.x >> 6, lane = threadIdx.x & 63;
    const int v = blockIdx.x * 4 + wave;
    if (v >= N_NODES) return;
    int c = cnt_all[v]; if (c > CAPA) c = CAPA;
    const int* el = elist + (size_t)v * CAPA;
    float s0 = 0.f, s1 = 0.f, s2 = 0.f, s3 = 0.f;
    for (int e = 0; e < c; ++e) {
        const int packed = el[e];
        f16x4 y = *reinterpret_cast<const f16x4*>(&Y[(size_t)packed * 256 + lane * 4]);
        s0 += (float)y[0]; s1 += (float)y[1]; s2 += (float)y[2]; s3 += (float)y[3];
    }
    const float4* bm = reinterpret_cast<const float4*>(b_msg + (size_t)layer * 1024);
    #pragma unroll
    for (int tt = 0; tt < 4; ++tt) {
        const float fc = (float)cnt4[tt * N_NODES + v];
        float4 b = bm[tt * 64 + lane];
        s0 += fc * b.x; s1 += fc * b.y; s2 += fc * b.z; s3 += fc * b.w;
    }
    f16x4 o; o[0] = (half_t)s0; o[1] = (half_t)s1; o[2] = (half_t)s2; o[3] = (half_t)s3;
    *reinterpret_cast<f16x4*>(&inc16[(size_t)v * 256 + lane * 4]) = o;
}

// ---------------- k_gru6: fused GRU; A in regs, B-only LDS dbuf, yb = blockIdx.y ----------------
// grid (782, 2); BM=64, 128 h-cols x 3 gates; 8 waves (rh2 x wc4), wave 32 rows x 32 cols x 3g
#define GRU6_STAGE(cc, DST) do {                                                       \
    const half_t* sn_ = pB + (size_t)(cc) * 12288;                                     \
    gload16(sn_ + t * 8,        (DST) + t * 8);                                        \
    gload16(sn_ + 4096 + t * 8, (DST) + 4096 + t * 8);                                 \
    gload16(sn_ + 8192 + t * 8, (DST) + 8192 + t * 8);                                 \
} while (0)

#define GRU6_LOADA(AF, cc) do {                                                        \
    const int c_ = (cc);                                                               \
    _Pragma("unroll") for (int rt = 0; rt < 2; ++rt)                                   \
        (AF)[rt] = *reinterpret_cast<const f16x8*>(                                    \
            (c_ < 8 ? apH[rt] : apI[rt]) + (c_ & 7) * 32);                             \
} while (0)

#define GRU6_COMP(AF, BUF, AN) do {                                                    \
    const half_t* Bq_ = (BUF) + (size_t)(kc * 384 + wc * 32 + rl) * 8;                 \
    _Pragma("unroll") for (int nt = 0; nt < 2; ++nt) {                                 \
        f16x8 br_ = *reinterpret_cast<const f16x8*>(Bq_ + nt * 128);                   \
        f16x8 bz_ = *reinterpret_cast<const f16x8*>(Bq_ + 1024 + nt * 128);            \
        f16x8 bn_ = *reinterpret_cast<const f16x8*>(Bq_ + 2048 + nt * 128);            \
        _Pragma("unroll") for (int rt = 0; rt < 2; ++rt) {                             \
            ar[rt][nt] = MFMA16((AF)[rt], br_, ar[rt][nt]);                            \
            az[rt][nt] = MFMA16((AF)[rt], bz_, az[rt][nt]);                            \
            AN[rt][nt] = MFMA16((AF)[rt], bn_, AN[rt][nt]);                            \
        }                                                                              \
    }                                                                                  \
} while (0)

__global__ __launch_bounds__(512, 6) void k_gru6(
    const half_t* __restrict__ h16in, const half_t* __restrict__ inc16,
    half_t* __restrict__ h16out, float* __restrict__ out32,
    const half_t* __restrict__ Wg,
    const float* __restrict__ b_ih, const float* __restrict__ b_hh,
    int layer, int last)
{
    __shared__ __align__(16) half_t lds[24576];   // bufs 2x12288 (48 KB)
    const int t = threadIdx.x, lane = t & 63;
    const int rh = (t >> 6) >> 2, wc = (t >> 6) & 3;
    const int n0 = blockIdx.x * 64, yb = blockIdx.y;
    const int kc = lane >> 4, rl = lane & 15;

    const half_t* apH[2];
    const half_t* apI[2];
    #pragma unroll
    for (int rt = 0; rt < 2; ++rt) {
        int node = n0 + rh * 32 + rt * 16 + rl;
        if (node > N_NODES - 1) node = N_NODES - 1;
        apH[rt] = h16in + (size_t)node * 256 + kc * 8;
        apI[rt] = inc16 + (size_t)node * 256 + kc * 8;
    }
    const half_t* pB = Wg + (size_t)(layer * 2 + yb) * 196608;
    half_t* buf0 = lds; half_t* buf1 = lds + 12288;

    f32x4 ar[2][2] = {}, az[2][2] = {}, ahn[2][2] = {}, ain[2][2] = {};
    f16x8 afA[2], afB[2];

    GRU6_STAGE(0, buf0);
    GRU6_LOADA(afA, 0);
    __syncthreads();

    #pragma unroll 1
    for (int p = 0; p < 4; ++p) {           // chunks 0..7: h-part, n-gate -> ahn
        GRU6_STAGE(2 * p + 1, buf1);
        GRU6_LOADA(afB, 2 * p + 1);
        GRU6_COMP(afA, buf0, ahn);
        __syncthreads();
        GRU6_STAGE(2 * p + 2, buf0);        // at p=3 this stages chunk 8 (inc-part)
        GRU6_LOADA(afA, 2 * p + 2);
        GRU6_COMP(afB, buf1, ahn);
        __syncthreads();
    }
    #pragma unroll 1
    for (int p = 4; p < 8; ++p) {           // chunks 8..15: inc-part, n-gate -> ain
        GRU6_STAGE(2 * p + 1, buf1);
        GRU6_LOADA(afB, 2 * p + 1);
        GRU6_COMP(afA, buf0, ain);
        __syncthreads();
        if (p < 7) {
            GRU6_STAGE(2 * p + 2, buf0);
            GRU6_LOADA(afA, 2 * p + 2);
        }
        GRU6_COMP(afB, buf1, ain);
        __syncthreads();
    }

    // GRU elementwise epilogue
    const int rg = kc;
    const float* bi = b_ih + layer * 768;
    const float* bh = b_hh + layer * 768;
    #pragma unroll
    for (int rt = 0; rt < 2; ++rt)
        #pragma unroll
        for (int i = 0; i < 4; ++i) {
            const int row = n0 + rh * 32 + rt * 16 + rg * 4 + i;
            const bool ok = row < N_NODES;
            #pragma unroll
            for (int nt = 0; nt < 2; ++nt) {
                const int col = yb * 128 + wc * 32 + nt * 16 + rl;
                float sr  = ar [rt][nt][i] + bi[col]       + bh[col];
                float sz  = az [rt][nt][i] + bi[256 + col] + bh[256 + col];
                float xin = ain[rt][nt][i] + bi[512 + col];
                float xhn = ahn[rt][nt][i] + bh[512 + col];
                float r = 1.f / (1.f + __expf(-sr));
                float z = 1.f / (1.f + __expf(-sz));
                float a = xin + r * xhn;
                float e2 = __expf(2.f * a);
                float n = (e2 - 1.f) / (e2 + 1.f);
                float hold = ok ? (float)h16in[(size_t)row * 256 + col] : 0.f;
                ar[rt][nt][i] = (1.f - z) * n + z * hold;
            }
        }

    if (!last) {
        // fp16 store via LDS transpose [64][136]
        #pragma unroll
        for (int rt = 0; rt < 2; ++rt)
            #pragma unroll
            for (int i = 0; i < 4; ++i) {
                const int rr = rh * 32 + rt * 16 + rg * 4 + i;
                #pragma unroll
                for (int nt = 0; nt < 2; ++nt)
                    lds[rr * 136 + wc * 32 + nt * 16 + rl] = (half_t)ar[rt][nt][i];
            }
        __syncthreads();
        #pragma unroll
        for (int p = 0; p < 2; ++p) {
            const int g = p * 512 + t, row = g >> 4, q = g & 15;
            if (n0 + row < N_NODES)
                *reinterpret_cast<f16x8*>(&h16out[(size_t)(n0 + row) * 256 + yb * 128 + q * 8]) =
                    *reinterpret_cast<const f16x8*>(&lds[row * 136 + q * 8]);
        }
    } else {
        #pragma unroll
        for (int rt = 0; rt < 2; ++rt)
            #pragma unroll
            for (int i = 0; i < 4; ++i) {
                const int row = n0 + rh * 32 + rt * 16 + rg * 4 + i;
                if (row >= N_NODES) continue;
                #pragma unroll
                for (int nt = 0; nt < 2; ++nt) {
                    const int col = yb * 128 + wc * 32 + nt * 16 + rl;
                    out32[(size_t)row * 256 + col] = ar[rt][nt][i];
                }
            }
    }
}

// ---------------- launcher ----------------
extern "C" void kernel_launch(void* const* d_in, const int* in_sizes, int n_in,
                              void* d_out, int out_size, void* d_ws, size_t ws_size,
                              hipStream_t stream) {
    const float* x      = (const float*)d_in[0];
    const float* annot  = (const float*)d_in[1];
    const int*   edges  = (const int*)  d_in[2];
    const float* W_hid  = (const float*)d_in[3];
    const float* b_hid  = (const float*)d_in[4];
    const float* W_msg  = (const float*)d_in[5];
    const float* b_msg  = (const float*)d_in[6];
    const float* W_ih   = (const float*)d_in[7];
    const float* W_hh   = (const float*)d_in[8];
    const float* b_ih   = (const float*)d_in[9];
    const float* b_hh   = (const float*)d_in[10];

    char* ws = (char*)d_ws;
    size_t off = 0;
    auto alloc = [&](size_t bytes) -> char* {
        char* p = ws + off;
        off = (off + bytes + 255) & ~(size_t)255;
        return p;
    };
    half_t* hA      = (half_t*)alloc((size_t)N_NODES * 256 * 2);          // 25.6 MB
    half_t* hB      = (half_t*)alloc((size_t)N_NODES * 256 * 2);          // 25.6 MB
    half_t* inc16   = (half_t*)alloc((size_t)N_NODES * 256 * 2);          // 25.6 MB
    half_t* Y       = (half_t*)alloc((size_t)N_NODES * 1024 * 2);         // 102.4 MB
    int*    elist   = (int*)   alloc((size_t)N_NODES * CAPA * 4);         // 6.4 MB
    int*    cnt_all = (int*)   alloc((size_t)N_NODES * 4);
    int*    cnt4    = (int*)   alloc((size_t)NTYPES * N_NODES * 4);
    half_t* Whid16  = (half_t*)alloc((size_t)256 * 288 * 2);
    half_t* Wg      = (half_t*)alloc((size_t)786432 * 2);
    half_t* Wy      = (half_t*)alloc((size_t)524288 * 2);
    (void)ws_size;

    hipMemsetAsync(cnt_all, 0, (size_t)N_NODES * 4, stream);
    hipMemsetAsync(cnt4,    0, (size_t)NTYPES * N_NODES * 4, stream);
    k_csr2<<<dim3((NTYPES * EPT + 255) / 256), 256, 0, stream>>>(edges, cnt_all, cnt4, elist);
    k_cvt<<<dim3((73728 + 255) / 256), 256, 0, stream>>>(W_hid, Whid16, 73728);
    k_cvt_wg<<<dim3(786432 / 256), 256, 0, stream>>>(W_ih, W_hh, Wg);
    k_cvt_wy<<<dim3(524288 / 256), 256, 0, stream>>>(W_msg, Wy);

    const int NB = (N_NODES + 63) / 64;   // 782
    k_init<<<dim3(NB), 256, 0, stream>>>(x, annot, Whid16, b_hid, hA);

    for (int step = 0; step < 6; ++step) {
        const int layer = step / 3;
        half_t* hin  = (step & 1) ? hB : hA;
        half_t* hout = (step & 1) ? hA : hB;
        const int last = (step == 5) ? 1 : 0;
        k_y5<<<dim3(NB, 4), 512, 0, stream>>>(hin, Wy, Y, layer);
        k_gather2<<<dim3((N_NODES + 3) / 4), 256, 0, stream>>>(
            Y, cnt_all, cnt4, elist, b_msg, inc16, layer);
        k_gru6<<<dim3(NB, 2), 512, 0, stream>>>(
            hin, inc16, hout, (float*)d_out, Wg, b_ih, b_hh, layer, last);
    }
}

// Round 8
// 1401.054 us; speedup vs baseline: 1.4017x; 1.4017x over previous
//
#include <hip/hip_runtime.h>

#define N_NODES 50000
#define HIDDEN  256
#define ANNOT   32
#define NTYPES  4
#define EPT     75000
#define CAPA    32   // total in-degree cap; Poisson(6) -> P(>32) ~ 1e-16

typedef __attribute__((ext_vector_type(4))) float    f32x4;
typedef __attribute__((ext_vector_type(8))) _Float16 f16x8;
typedef __attribute__((ext_vector_type(4))) _Float16 f16x4;
typedef _Float16 half_t;

#define MFMA16(a,b,c) __builtin_amdgcn_mfma_f32_16x16x32_f16((a),(b),(c),0,0,0)

__device__ __forceinline__ void gload16(const void* g, void* l) {
    __builtin_amdgcn_global_load_lds((const __attribute__((address_space(1))) void*)g,
                                     (__attribute__((address_space(3))) void*)l, 16, 0, 0);
}

// ---------------- flat fp32 -> fp16 convert ----------------
__global__ void k_cvt(const float* __restrict__ in, half_t* __restrict__ out, int n) {
    int i = blockIdx.x * blockDim.x + threadIdx.x;
    if (i < n) out[i] = (half_t)in[i];
}

// GRU weights -> [layer][yb2][chunk16][kc4][gcol384][e8]
// K axis: chunks 0-7 = h-part (Whh), 8-15 = inc-part (Wih); gcol = gate*128 + cl
__global__ void k_cvt_wg(const float* __restrict__ Wih, const float* __restrict__ Whh,
                         half_t* __restrict__ out) {
    int i = blockIdx.x * blockDim.x + threadIdx.x;
    if (i >= 786432) return;
    const int e = i & 7; int idx = i >> 3;
    const int gcol = idx % 384; idx /= 384;
    const int kc = idx & 3; idx >>= 2;
    const int chunk = idx & 15; idx >>= 4;
    const int yb = idx & 1;
    const int layer = idx >> 1;
    const int gate = gcol >> 7, cl = gcol & 127;
    const int k = chunk * 32 + kc * 8 + e;
    const int colf = gate * 256 + yb * 128 + cl;
    float v = (k < 256) ? Whh[((size_t)layer * 768 + colf) * 256 + k]
                        : Wih[((size_t)layer * 768 + colf) * 256 + (k - 256)];
    out[i] = (half_t)v;
}

// message weights -> [layer][yb4][chunk8][kc4][col256][e8]; Y col = yb*256+col (yb==type)
__global__ void k_cvt_wy(const float* __restrict__ Wmsg, half_t* __restrict__ out) {
    int i = blockIdx.x * blockDim.x + threadIdx.x;
    if (i >= 524288) return;
    const int e = i & 7; int idx = i >> 3;
    const int col = idx & 255; idx >>= 8;
    const int kc = idx & 3; idx >>= 2;
    const int chunk = idx & 7; idx >>= 3;
    const int yb = idx & 3;
    const int layer = idx >> 2;
    const int k = chunk * 32 + kc * 8 + e;
    out[i] = (half_t)Wmsg[(((size_t)layer * 4 + yb) * 256 + col) * 256 + k];
}

// ---------------- merged CSR: per-target packed (src*4 + type) list ----------------
__global__ void k_csr2(const int* __restrict__ edges, int* __restrict__ cnt_all,
                       int* __restrict__ cnt4, int* __restrict__ elist) {
    int i = blockIdx.x * blockDim.x + threadIdx.x;
    if (i >= NTYPES * EPT) return;
    int2 st = *reinterpret_cast<const int2*>(&edges[(size_t)i * 2]);
    const int tt = i / EPT;
    atomicAdd(&cnt4[tt * N_NODES + st.y], 1);
    int pos = atomicAdd(&cnt_all[st.y], 1);
    if (pos < CAPA) elist[(size_t)st.y * CAPA + pos] = st.x * 4 + tt;
}

// ---------------- h0 = [x | annot] @ W_hid^T + b_hid  (runs once) ----------------
__global__ __launch_bounds__(256) void k_init(
    const float* __restrict__ x, const float* __restrict__ annot,
    const half_t* __restrict__ Whid16, const float* __restrict__ b_hid,
    half_t* __restrict__ h16out)
{
    __shared__ __align__(16) half_t Atile[4 * 64 * 8];
    const int tid  = threadIdx.x;
    const int lane = tid & 63;
    const int wave = tid >> 6;
    const int n0   = blockIdx.x * 64;

    f32x4 acc[4][4] = {};

    for (int ks = 0; ks < 9; ++ks) {
        const int k0 = ks * 32;
        {
            const int c = tid >> 6, r = tid & 63;
            const int node = n0 + r;
            f16x8 hv = {};
            if (node < N_NODES) {
                const int kk = k0 + c * 8;
                const float* s = (kk < HIDDEN) ? (x + (size_t)node * HIDDEN + kk)
                                               : (annot + (size_t)node * ANNOT + (kk - HIDDEN));
                const float4* s4 = reinterpret_cast<const float4*>(s);
                float4 a0 = s4[0], a1 = s4[1];
                hv[0]=(half_t)a0.x; hv[1]=(half_t)a0.y; hv[2]=(half_t)a0.z; hv[3]=(half_t)a0.w;
                hv[4]=(half_t)a1.x; hv[5]=(half_t)a1.y; hv[6]=(half_t)a1.z; hv[7]=(half_t)a1.w;
            }
            *reinterpret_cast<f16x8*>(&Atile[(c * 64 + r) * 8]) = hv;
        }
        __syncthreads();
        const int kc = lane >> 4, rl = lane & 15;
        f16x8 af[4];
        #pragma unroll
        for (int rt = 0; rt < 4; ++rt)
            af[rt] = *reinterpret_cast<const f16x8*>(&Atile[(kc * 64 + rt * 16 + rl) * 8]);
        #pragma unroll
        for (int nt = 0; nt < 4; ++nt) {
            const int col = wave * 64 + nt * 16 + rl;
            f16x8 bf = *reinterpret_cast<const f16x8*>(&Whid16[col * 288 + k0 + kc * 8]);
            #pragma unroll
            for (int rt = 0; rt < 4; ++rt)
                acc[rt][nt] = MFMA16(af[rt], bf, acc[rt][nt]);
        }
        __syncthreads();
    }

    const int rl = lane & 15, rg = lane >> 4;
    #pragma unroll
    for (int rt = 0; rt < 4; ++rt)
        #pragma unroll
        for (int i = 0; i < 4; ++i) {
            const int row = n0 + rt * 16 + rg * 4 + i;
            if (row >= N_NODES) continue;
            #pragma unroll
            for (int nt = 0; nt < 4; ++nt) {
                const int col = wave * 64 + nt * 16 + rl;
                h16out[(size_t)row * 256 + col] = (half_t)(acc[rt][nt][i] + b_hid[col]);
            }
        }
}

// ---------------- k_y5: Y[:, yb*256..] = h16 @ W^T; A in regs, B-only LDS dbuf ----------------
// grid (782, 4), 512 thr / 8 waves (rh2 x wc4); BM=64, wave 32 rows x 64 cols; K=256, BK=32
#define Y5_STAGE(cc, DST) do {                                                         \
    const half_t* sn_ = pBy + (size_t)(cc) * 8192;                                     \
    gload16(sn_ + t * 8,        (DST) + t * 8);                                        \
    gload16(sn_ + 4096 + t * 8, (DST) + 4096 + t * 8);                                 \
} while (0)

#define Y5_LOADA(AF, cc) do {                                                          \
    _Pragma("unroll") for (int rt = 0; rt < 2; ++rt)                                   \
        (AF)[rt] = *reinterpret_cast<const f16x8*>(apY[rt] + (cc) * 32);               \
} while (0)

#define Y5_COMP(AF, BUF) do {                                                          \
    const half_t* Bq_ = (BUF) + (size_t)(kc * 256 + wc * 64 + rl) * 8;                 \
    _Pragma("unroll") for (int nt = 0; nt < 4; ++nt) {                                 \
        f16x8 bf_ = *reinterpret_cast<const f16x8*>(Bq_ + nt * 128);                   \
        _Pragma("unroll") for (int rt = 0; rt < 2; ++rt)                               \
            acc[rt][nt] = MFMA16((AF)[rt], bf_, acc[rt][nt]);                          \
    }                                                                                  \
} while (0)

__global__ __launch_bounds__(512, 2) void k_y5(
    const half_t* __restrict__ h16in, const half_t* __restrict__ Wy,
    half_t* __restrict__ Y, int layer)
{
    __shared__ __align__(16) half_t lds[16896];   // bufs 2x8192; reused as OutT [64][264]
    const int t = threadIdx.x, lane = t & 63;
    const int rh = (t >> 6) >> 2, wc = (t >> 6) & 3;
    const int n0 = blockIdx.x * 64, yb = blockIdx.y;
    const int kc = lane >> 4, rl = lane & 15;

    const half_t* apY[2];
    #pragma unroll
    for (int rt = 0; rt < 2; ++rt) {
        int node = n0 + rh * 32 + rt * 16 + rl;
        if (node > N_NODES - 1) node = N_NODES - 1;
        apY[rt] = h16in + (size_t)node * 256 + kc * 8;
    }
    const half_t* pBy = Wy + (size_t)(layer * 4 + yb) * 65536;
    half_t* buf0 = lds; half_t* buf1 = lds + 8192;

    f32x4 acc[2][4] = {};
    f16x8 afA[2], afB[2];

    Y5_STAGE(0, buf0);
    Y5_LOADA(afA, 0);
    __syncthreads();

    #pragma unroll 1
    for (int p = 0; p < 4; ++p) {
        Y5_STAGE(2 * p + 1, buf1);
        Y5_LOADA(afB, 2 * p + 1);
        Y5_COMP(afA, buf0);
        __syncthreads();
        if (p < 3) {
            Y5_STAGE(2 * p + 2, buf0);
            Y5_LOADA(afA, 2 * p + 2);
        }
        Y5_COMP(afB, buf1);
        __syncthreads();
    }

    // epilogue: transpose [64][264] in lds, coalesced f16x8 stores
    const int rg = kc;
    #pragma unroll
    for (int rt = 0; rt < 2; ++rt)
        #pragma unroll
        for (int i = 0; i < 4; ++i) {
            const int row = rh * 32 + rt * 16 + rg * 4 + i;
            #pragma unroll
            for (int nt = 0; nt < 4; ++nt)
                lds[row * 264 + wc * 64 + nt * 16 + rl] = (half_t)acc[rt][nt][i];
        }
    __syncthreads();
    #pragma unroll
    for (int p = 0; p < 4; ++p) {
        const int g = p * 512 + t, row = g >> 5, q = g & 31;
        if (n0 + row < N_NODES)
            *reinterpret_cast<f16x8*>(&Y[(size_t)(n0 + row) * 1024 + yb * 256 + q * 8]) =
                *reinterpret_cast<const f16x8*>(&lds[row * 264 + q * 8]);
    }
}

// ---------------- k_gather2: inc[v] = sum_e Y[packed_e] + sum_t cnt_t * b_t ----------------
__global__ __launch_bounds__(256) void k_gather2(
    const half_t* __restrict__ Y, const int* __restrict__ cnt_all,
    const int* __restrict__ cnt4, const int* __restrict__ elist,
    const float* __restrict__ b_msg, half_t* __restrict__ inc16, int layer)
{
    const int wave = threadIdx.x >> 6, lane = threadIdx.x & 63;
    const int v = blockIdx.x * 4 + wave;
    if (v >= N_NODES) return;
    int c = cnt_all[v]; if (c > CAPA) c = CAPA;
    const int* el = elist + (size_t)v * CAPA;
    float s0 = 0.f, s1 = 0.f, s2 = 0.f, s3 = 0.f;
    for (int e = 0; e < c; ++e) {
        const int packed = el[e];
        f16x4 y = *reinterpret_cast<const f16x4*>(&Y[(size_t)packed * 256 + lane * 4]);
        s0 += (float)y[0]; s1 += (float)y[1]; s2 += (float)y[2]; s3 += (float)y[3];
    }
    const float4* bm = reinterpret_cast<const float4*>(b_msg + (size_t)layer * 1024);
    #pragma unroll
    for (int tt = 0; tt < 4; ++tt) {
        const float fc = (float)cnt4[tt * N_NODES + v];
        float4 b = bm[tt * 64 + lane];
        s0 += fc * b.x; s1 += fc * b.y; s2 += fc * b.z; s3 += fc * b.w;
    }
    f16x4 o; o[0] = (half_t)s0; o[1] = (half_t)s1; o[2] = (half_t)s2; o[3] = (half_t)s3;
    *reinterpret_cast<f16x4*>(&inc16[(size_t)v * 256 + lane * 4]) = o;
}

// ---------------- k_gru6: fused GRU; A in regs, B-only LDS dbuf, yb = blockIdx.y ----------------
// grid (782, 2); BM=64, 128 h-cols x 3 gates; 8 waves (rh2 x wc4), wave 32 rows x 32 cols x 3g
#define GRU6_STAGE(cc, DST) do {                                                       \
    const half_t* sn_ = pB + (size_t)(cc) * 12288;                                     \
    gload16(sn_ + t * 8,        (DST) + t * 8);                                        \
    gload16(sn_ + 4096 + t * 8, (DST) + 4096 + t * 8);                                 \
    gload16(sn_ + 8192 + t * 8, (DST) + 8192 + t * 8);                                 \
} while (0)

#define GRU6_LOADA(AF, cc) do {                                                        \
    const int c_ = (cc);                                                               \
    _Pragma("unroll") for (int rt = 0; rt < 2; ++rt)                                   \
        (AF)[rt] = *reinterpret_cast<const f16x8*>(                                    \
            (c_ < 8 ? apH[rt] : apI[rt]) + (c_ & 7) * 32);                             \
} while (0)

#define GRU6_COMP(AF, BUF, AN) do {                                                    \
    const half_t* Bq_ = (BUF) + (size_t)(kc * 384 + wc * 32 + rl) * 8;                 \
    _Pragma("unroll") for (int nt = 0; nt < 2; ++nt) {                                 \
        f16x8 br_ = *reinterpret_cast<const f16x8*>(Bq_ + nt * 128);                   \
        f16x8 bz_ = *reinterpret_cast<const f16x8*>(Bq_ + 1024 + nt * 128);            \
        f16x8 bn_ = *reinterpret_cast<const f16x8*>(Bq_ + 2048 + nt * 128);            \
        _Pragma("unroll") for (int rt = 0; rt < 2; ++rt) {                             \
            ar[rt][nt] = MFMA16((AF)[rt], br_, ar[rt][nt]);                            \
            az[rt][nt] = MFMA16((AF)[rt], bz_, az[rt][nt]);                            \
            AN[rt][nt] = MFMA16((AF)[rt], bn_, AN[rt][nt]);                            \
        }                                                                              \
    }                                                                                  \
} while (0)

__global__ __launch_bounds__(512, 2) void k_gru6(
    const half_t* __restrict__ h16in, const half_t* __restrict__ inc16,
    half_t* __restrict__ h16out, float* __restrict__ out32,
    const half_t* __restrict__ Wg,
    const float* __restrict__ b_ih, const float* __restrict__ b_hh,
    int layer, int last)
{
    __shared__ __align__(16) half_t lds[24576];   // bufs 2x12288 (48 KB)
    const int t = threadIdx.x, lane = t & 63;
    const int rh = (t >> 6) >> 2, wc = (t >> 6) & 3;
    const int n0 = blockIdx.x * 64, yb = blockIdx.y;
    const int kc = lane >> 4, rl = lane & 15;

    const half_t* apH[2];
    const half_t* apI[2];
    #pragma unroll
    for (int rt = 0; rt < 2; ++rt) {
        int node = n0 + rh * 32 + rt * 16 + rl;
        if (node > N_NODES - 1) node = N_NODES - 1;
        apH[rt] = h16in + (size_t)node * 256 + kc * 8;
        apI[rt] = inc16 + (size_t)node * 256 + kc * 8;
    }
    const half_t* pB = Wg + (size_t)(layer * 2 + yb) * 196608;
    half_t* buf0 = lds; half_t* buf1 = lds + 12288;

    f32x4 ar[2][2] = {}, az[2][2] = {}, ahn[2][2] = {}, ain[2][2] = {};
    f16x8 afA[2], afB[2];

    GRU6_STAGE(0, buf0);
    GRU6_LOADA(afA, 0);
    __syncthreads();

    #pragma unroll 1
    for (int p = 0; p < 4; ++p) {           // chunks 0..7: h-part, n-gate -> ahn
        GRU6_STAGE(2 * p + 1, buf1);
        GRU6_LOADA(afB, 2 * p + 1);
        GRU6_COMP(afA, buf0, ahn);
        __syncthreads();
        GRU6_STAGE(2 * p + 2, buf0);        // at p=3 this stages chunk 8 (inc-part)
        GRU6_LOADA(afA, 2 * p + 2);
        GRU6_COMP(afB, buf1, ahn);
        __syncthreads();
    }
    #pragma unroll 1
    for (int p = 4; p < 8; ++p) {           // chunks 8..15: inc-part, n-gate -> ain
        GRU6_STAGE(2 * p + 1, buf1);
        GRU6_LOADA(afB, 2 * p + 1);
        GRU6_COMP(afA, buf0, ain);
        __syncthreads();
        if (p < 7) {
            GRU6_STAGE(2 * p + 2, buf0);
            GRU6_LOADA(afA, 2 * p + 2);
        }
        GRU6_COMP(afB, buf1, ain);
        __syncthreads();
    }

    // GRU elementwise epilogue
    const int rg = kc;
    const float* bi = b_ih + layer * 768;
    const float* bh = b_hh + layer * 768;
    #pragma unroll
    for (int rt = 0; rt < 2; ++rt)
        #pragma unroll
        for (int i = 0; i < 4; ++i) {
            const int row = n0 + rh * 32 + rt * 16 + rg * 4 + i;
            const bool ok = row < N_NODES;
            #pragma unroll
            for (int nt = 0; nt < 2; ++nt) {
                const int col = yb * 128 + wc * 32 + nt * 16 + rl;
                float sr  = ar [rt][nt][i] + bi[col]       + bh[col];
                float sz  = az [rt][nt][i] + bi[256 + col] + bh[256 + col];
                float xin = ain[rt][nt][i] + bi[512 + col];
                float xhn = ahn[rt][nt][i] + bh[512 + col];
                float r = 1.f / (1.f + __expf(-sr));
                float z = 1.f / (1.f + __expf(-sz));
                float a = xin + r * xhn;
                float e2 = __expf(2.f * a);
                float n = (e2 - 1.f) / (e2 + 1.f);
                float hold = ok ? (float)h16in[(size_t)row * 256 + col] : 0.f;
                ar[rt][nt][i] = (1.f - z) * n + z * hold;
            }
        }

    if (!last) {
        // fp16 store via LDS transpose [64][136]
        #pragma unroll
        for (int rt = 0; rt < 2; ++rt)
            #pragma unroll
            for (int i = 0; i < 4; ++i) {
                const int rr = rh * 32 + rt * 16 + rg * 4 + i;
                #pragma unroll
                for (int nt = 0; nt < 2; ++nt)
                    lds[rr * 136 + wc * 32 + nt * 16 + rl] = (half_t)ar[rt][nt][i];
            }
        __syncthreads();
        #pragma unroll
        for (int p = 0; p < 2; ++p) {
            const int g = p * 512 + t, row = g >> 4, q = g & 15;
            if (n0 + row < N_NODES)
                *reinterpret_cast<f16x8*>(&h16out[(size_t)(n0 + row) * 256 + yb * 128 + q * 8]) =
                    *reinterpret_cast<const f16x8*>(&lds[row * 136 + q * 8]);
        }
    } else {
        #pragma unroll
        for (int rt = 0; rt < 2; ++rt)
            #pragma unroll
            for (int i = 0; i < 4; ++i) {
                const int row = n0 + rh * 32 + rt * 16 + rg * 4 + i;
                if (row >= N_NODES) continue;
                #pragma unroll
                for (int nt = 0; nt < 2; ++nt) {
                    const int col = yb * 128 + wc * 32 + nt * 16 + rl;
                    out32[(size_t)row * 256 + col] = ar[rt][nt][i];
                }
            }
    }
}

// ---------------- launcher ----------------
extern "C" void kernel_launch(void* const* d_in, const int* in_sizes, int n_in,
                              void* d_out, int out_size, void* d_ws, size_t ws_size,
                              hipStream_t stream) {
    const float* x      = (const float*)d_in[0];
    const float* annot  = (const float*)d_in[1];
    const int*   edges  = (const int*)  d_in[2];
    const float* W_hid  = (const float*)d_in[3];
    const float* b_hid  = (const float*)d_in[4];
    const float* W_msg  = (const float*)d_in[5];
    const float* b_msg  = (const float*)d_in[6];
    const float* W_ih   = (const float*)d_in[7];
    const float* W_hh   = (const float*)d_in[8];
    const float* b_ih   = (const float*)d_in[9];
    const float* b_hh   = (const float*)d_in[10];

    char* ws = (char*)d_ws;
    size_t off = 0;
    auto alloc = [&](size_t bytes) -> char* {
        char* p = ws + off;
        off = (off + bytes + 255) & ~(size_t)255;
        return p;
    };
    half_t* hA      = (half_t*)alloc((size_t)N_NODES * 256 * 2);          // 25.6 MB
    half_t* hB      = (half_t*)alloc((size_t)N_NODES * 256 * 2);          // 25.6 MB
    half_t* inc16   = (half_t*)alloc((size_t)N_NODES * 256 * 2);          // 25.6 MB
    half_t* Y       = (half_t*)alloc((size_t)N_NODES * 1024 * 2);         // 102.4 MB
    int*    elist   = (int*)   alloc((size_t)N_NODES * CAPA * 4);         // 6.4 MB
    int*    cnt_all = (int*)   alloc((size_t)N_NODES * 4);
    int*    cnt4    = (int*)   alloc((size_t)NTYPES * N_NODES * 4);
    half_t* Whid16  = (half_t*)alloc((size_t)256 * 288 * 2);
    half_t* Wg      = (half_t*)alloc((size_t)786432 * 2);
    half_t* Wy      = (half_t*)alloc((size_t)524288 * 2);
    (void)ws_size;

    hipMemsetAsync(cnt_all, 0, (size_t)N_NODES * 4, stream);
    hipMemsetAsync(cnt4,    0, (size_t)NTYPES * N_NODES * 4, stream);
    k_csr2<<<dim3((NTYPES * EPT + 255) / 256), 256, 0, stream>>>(edges, cnt_all, cnt4, elist);
    k_cvt<<<dim3((73728 + 255) / 256), 256, 0, stream>>>(W_hid, Whid16, 73728);
    k_cvt_wg<<<dim3(786432 / 256), 256, 0, stream>>>(W_ih, W_hh, Wg);
    k_cvt_wy<<<dim3(524288 / 256), 256, 0, stream>>>(W_msg, Wy);

    const int NB = (N_NODES + 63) / 64;   // 782
    k_init<<<dim3(NB), 256, 0, stream>>>(x, annot, Whid16, b_hid, hA);

    for (int step = 0; step < 6; ++step) {
        const int layer = step / 3;
        half_t* hin  = (step & 1) ? hB : hA;
        half_t* hout = (step & 1) ? hA : hB;
        const int last = (step == 5) ? 1 : 0;
        k_y5<<<dim3(NB, 4), 512, 0, stream>>>(hin, Wy, Y, layer);
        k_gather2<<<dim3((N_NODES + 3) / 4), 256, 0, stream>>>(
            Y, cnt_all, cnt4, elist, b_msg, inc16, layer);
        k_gru6<<<dim3(NB, 2), 512, 0, stream>>>(
            hin, inc16, hout, (float*)d_out, Wg, b_ih, b_hh, layer, last);
    }
}